// Round 7
// baseline (7637.267 us; speedup 1.0000x reference)
//
#include <hip/hip_runtime.h>
#include <math.h>

#define NRAYS 262144
#define MAXIT 192
#define NEARV 0.2f
#define FARV  2.0f
#define EPSV  0.001f
#define KCHUNK 16
#define NROUNDS 12   // KCHUNK * NROUNDS == MAXIT

// ---------------------------------------------------------------------------
// Single-ray SDF MLP eval (fallback path only) — canonical fma order,
// scalar weight loads.
// ---------------------------------------------------------------------------
__device__ __forceinline__ float sdf_eval(
    float px, float py, float pz,
    const float* __restrict__ W0, const float* __restrict__ b0,
    const float* __restrict__ W1, const float* __restrict__ b1,
    const float* __restrict__ W2, float b2_0)
{
    float h1[64];
    #pragma unroll
    for (int j = 0; j < 64; ++j) h1[j] = 0.f;

    for (int k = 0; k < 64; ++k) {
        float z = px * W0[k] + py * W0[64 + k] + pz * W0[128 + k];
        z += b0[k];
        const float a = fmaxf(z, 0.f);
        #pragma unroll
        for (int j = 0; j < 64; ++j) h1[j] = fmaf(a, W1[k * 64 + j], h1[j]);
    }

    float d = 0.f;
    #pragma unroll
    for (int j = 0; j < 64; ++j)
        d = fmaf(fmaxf(h1[j] + b1[j], 0.f), W2[j * 33], d);
    return d + b2_0;
}

// ---------------------------------------------------------------------------
// Round-based march: 2 rays/lane, W1 staged in LDS.
// WHY (R1/R2/R3/R6 evidence): W1 rows delivered via s_load land in SGPRs;
// a 64-float row = 64 SGPRs vs a 102-SGPR budget, so the compiler either
// exposes scalar-load latency every k (R1: 44% VALU eff) or j-splits into
// half-rows and re-streams z (R2/R6: +43% instructions). LDS fixes the
// register file: wave-uniform ds_read_b128 broadcasts (conflict-free) into
// VGPRs (512-reg budget -> full-row double-buffer, single-pass math).
// Dual rays make the math (>=280 cyc/row) cover the ds stream (~192
// cyc/row). fma chains per ray identical to sdf_eval -> bit-identical t/hit
// (same structure as R4, which passed with identical absmax).
// ---------------------------------------------------------------------------
__global__ __launch_bounds__(256, 2)
void march_round2(const float* __restrict__ rays,
                  const float* __restrict__ W0, const float* __restrict__ b0,
                  const float* __restrict__ W1, const float* __restrict__ b1,
                  const float* __restrict__ W2, const float* __restrict__ b2,
                  int round0, int it_base,
                  const int* __restrict__ in_cnt,
                  const int* __restrict__ in_idx, const float* __restrict__ in_cd,
                  int* __restrict__ out_cnt,
                  int* __restrict__ out_idx, float* __restrict__ out_cd,
                  float* __restrict__ t_out,
                  int* __restrict__ hitq, int* __restrict__ hit_cnt)
{
    __shared__ float4 sW1[1024];   // 16 KB: sW1[k*16+q] = W1[k*64+4q .. +3]

    // Stage W1 before ANY divergent exit (barrier executed by all threads).
    {
        const float4* w1g = reinterpret_cast<const float4*>(W1);
        for (int t = threadIdx.x; t < 1024; t += 256) sW1[t] = w1g[t];
    }
    __syncthreads();

    const int i    = blockIdx.x * 256 + threadIdx.x;   // pair index
    const int lane = threadIdx.x & 63;
    const int n    = round0 ? NRAYS : *in_cnt;

    const int sA = 2 * i, sB = 2 * i + 1;
    bool aliveA = (sA < n), aliveB = (sB < n);
    bool hitA = false, hitB = false;
    int  ridxA = 0, ridxB = 0;
    float cdA = NEARV, cdB = NEARV;
    int  itA = it_base, itB = it_base;

    if (aliveA) {
        if (round0) { ridxA = sA; } else { ridxA = in_idx[sA]; cdA = in_cd[sA]; }
    }
    if (aliveB) {
        if (round0) { ridxB = sB; } else { ridxB = in_idx[sB]; cdB = in_cd[sB]; }
    }
    if (__ballot(aliveA || aliveB) == 0ull) return;   // whole wave empty

    const float* rA = rays + (size_t)ridxA * 6;   // dead slots read ray 0
    const float oxA = rA[0], oyA = rA[1], ozA = rA[2];
    const float rdxA = rA[3], rdyA = rA[4], rdzA = rA[5];
    const float* rB = rays + (size_t)ridxB * 6;
    const float oxB = rB[0], oyB = rB[1], ozB = rB[2];
    const float rdxB = rB[3], rdyB = rB[4], rdzB = rB[5];
    const float b2_0 = b2[0];

    for (int s = 0; s < KCHUNK; ++s) {
        if (__ballot(aliveA || aliveB) == 0ull) break;

        const float pxA = oxA + rdxA * cdA;
        const float pyA = oyA + rdyA * cdA;
        const float pzA = ozA + rdzA * cdA;
        const float pxB = oxB + rdxB * cdB;
        const float pyB = oyB + rdyB * cdB;
        const float pzB = ozB + rdzB * cdB;

        float hA[64], hB[64];
        #pragma unroll
        for (int j = 0; j < 64; ++j) { hA[j] = 0.f; hB[j] = 0.f; }

        for (int k = 0; k < 64; ++k) {
            // z from the scalar path (W0/b0 are 1KB, K$-resident now).
            float zA = pxA * W0[k] + pyA * W0[64 + k] + pzA * W0[128 + k];
            zA += b0[k];
            float zB = pxB * W0[k] + pyB * W0[64 + k] + pzB * W0[128 + k];
            zB += b0[k];
            const float aA = fmaxf(zA, 0.f);
            const float aB = fmaxf(zB, 0.f);
            // W1 row from LDS: wave-uniform ds_read_b128 broadcast.
            const float4* wr = &sW1[k * 16];
            #pragma unroll
            for (int q = 0; q < 16; ++q) {
                const float4 w = wr[q];
                hA[4 * q + 0] = fmaf(aA, w.x, hA[4 * q + 0]);
                hB[4 * q + 0] = fmaf(aB, w.x, hB[4 * q + 0]);
                hA[4 * q + 1] = fmaf(aA, w.y, hA[4 * q + 1]);
                hB[4 * q + 1] = fmaf(aB, w.y, hB[4 * q + 1]);
                hA[4 * q + 2] = fmaf(aA, w.z, hA[4 * q + 2]);
                hB[4 * q + 2] = fmaf(aB, w.z, hB[4 * q + 2]);
                hA[4 * q + 3] = fmaf(aA, w.w, hA[4 * q + 3]);
                hB[4 * q + 3] = fmaf(aB, w.w, hB[4 * q + 3]);
            }
        }

        float dA = 0.f, dB = 0.f;
        #pragma unroll
        for (int j = 0; j < 64; ++j) {
            const float b = b1[j];
            const float w = W2[j * 33];
            dA = fmaf(fmaxf(hA[j] + b, 0.f), w, dA);
            dB = fmaf(fmaxf(hB[j] + b, 0.f), w, dB);
        }
        dA += b2_0;
        dB += b2_0;

        if (aliveA) {
            ++itA;
            if (dA < EPSV && cdA <= FARV) hitA = true;
            cdA += dA;
            if (hitA || cdA > FARV || itA >= MAXIT) {
                t_out[ridxA] = cdA;
                if (hitA) { const int p = atomicAdd(hit_cnt, 1); hitq[p] = ridxA; }
                aliveA = false;
            }
        }
        if (aliveB) {
            ++itB;
            if (dB < EPSV && cdB <= FARV) hitB = true;
            cdB += dB;
            if (hitB || cdB > FARV || itB >= MAXIT) {
                t_out[ridxB] = cdB;
                if (hitB) { const int p = atomicAdd(hit_cnt, 1); hitq[p] = ridxB; }
                aliveB = false;
            }
        }
    }

    // Wave-aggregated compaction of survivors (slot A then slot B).
    unsigned long long m = __ballot(aliveA);
    if (m != 0ull) {
        const int leader = __builtin_ctzll(m);
        int base = 0;
        if (lane == leader) base = atomicAdd(out_cnt, __builtin_popcountll(m));
        base = __shfl(base, leader);
        if (aliveA) {
            const int off = __builtin_popcountll(m & ((1ull << lane) - 1ull));
            out_idx[base + off] = ridxA;
            out_cd[base + off]  = cdA;
        }
    }
    m = __ballot(aliveB);
    if (m != 0ull) {
        const int leader = __builtin_ctzll(m);
        int base = 0;
        if (lane == leader) base = atomicAdd(out_cnt, __builtin_popcountll(m));
        base = __shfl(base, leader);
        if (aliveB) {
            const int off = __builtin_popcountll(m & ((1ull << lane) - 1ull));
            out_idx[base + off] = ridxB;
            out_cd[base + off]  = cdB;
        }
    }
}

// ---------------------------------------------------------------------------
// Shade only the hit rays (dense hit queue). Output memset to zero.
// Bit-identical arithmetic to the passing shade kernel.
// ---------------------------------------------------------------------------
__global__ __launch_bounds__(256, 2)
void shade_hit(const float* __restrict__ rays,
               const float* __restrict__ W0, const float* __restrict__ b0,
               const float* __restrict__ W1, const float* __restrict__ b1,
               const float* __restrict__ W2, const float* __restrict__ b2,
               const float* __restrict__ RW0, const float* __restrict__ Rb0,
               const float* __restrict__ RW1, const float* __restrict__ Rb1,
               const float* __restrict__ t_in,
               const int* __restrict__ hitq, const int* __restrict__ hit_cnt,
               float* __restrict__ out)
{
    const int n = *hit_cnt;
    if (blockIdx.x * 256 >= n) return;   // whole block empty -> skip staging

    __shared__ float sW0[3 * 64];
    __shared__ float sb0[64];
    __shared__ float sW1[64 * 64];
    __shared__ float sb1[64];
    __shared__ float sW2T[33 * 64];   // [c][j] = W2[j][c]
    __shared__ float sb2[33];
    __shared__ float sRW0T[64 * 48];  // [u][f] = RW0[f][u], padded 41->48
    __shared__ float sRb0[64];
    __shared__ float sRW1[64 * 3];
    __shared__ float sRb1[3];

    const int tid = threadIdx.x;
    for (int i = tid; i < 3 * 64; i += 256) sW0[i] = W0[i];
    for (int i = tid; i < 64 * 64; i += 256) sW1[i] = W1[i];
    for (int i = tid; i < 33 * 64; i += 256) {
        const int c = i >> 6, j = i & 63;
        sW2T[i] = W2[j * 33 + c];
    }
    for (int i = tid; i < 64 * 41; i += 256) {
        const int u = i / 41, f = i - u * 41;
        sRW0T[u * 48 + f] = RW0[f * 64 + u];
    }
    if (tid < 64) { sb0[tid] = b0[tid]; sb1[tid] = b1[tid]; sRb0[tid] = Rb0[tid]; }
    if (tid < 33) sb2[tid] = b2[tid];
    if (tid < 192) sRW1[tid] = RW1[tid];
    if (tid < 3) sRb1[tid] = Rb1[tid];
    __syncthreads();

    const int qi = blockIdx.x * 256 + tid;
    if (qi >= n) return;
    const int i = hitq[qi];

    const float* r = rays + (size_t)i * 6;
    const float cd = t_in[i];
    const float ox = r[0], oy = r[1], oz = r[2];
    const float dx = r[3], dy = r[4], dz = r[5];
    const float px = ox + dx * cd;
    const float py = oy + dy * cd;
    const float pz = oz + dz * cd;

    // ---- forward, layer 1 accumulation ----
    float h1[64];
    #pragma unroll
    for (int j = 0; j < 64; ++j) h1[j] = 0.f;

    for (int k = 0; k < 64; ++k) {
        float z = px * sW0[k] + py * sW0[64 + k] + pz * sW0[128 + k];
        z += sb0[k];
        const float a = fmaxf(z, 0.f);
        #pragma unroll
        for (int j = 0; j < 64; ++j) h1[j] = fmaf(a, sW1[k * 64 + j], h1[j]);
    }
    #pragma unroll
    for (int j = 0; j < 64; ++j) h1[j] = fmaxf(h1[j] + sb1[j], 0.f);

    // ---- latent = out[:,1:33] ----
    float lat[32];
    #pragma unroll
    for (int c = 1; c < 33; ++c) {
        float acc = 0.f;
        #pragma unroll
        for (int j = 0; j < 64; ++j) acc = fmaf(h1[j], sW2T[c * 64 + j], acc);
        lat[c - 1] = acc + sb2[c];
    }

    // ---- backward: gz1 = (z1>0) ? W2[:,0] : 0 ----
    #pragma unroll
    for (int j = 0; j < 64; ++j) h1[j] = (h1[j] > 0.f) ? sW2T[j] : 0.f;

    float nx = 0.f, ny = 0.f, nz = 0.f;
    for (int k = 0; k < 64; ++k) {
        float z = px * sW0[k] + py * sW0[64 + k] + pz * sW0[128 + k];
        z += sb0[k];
        float g = 0.f;
        #pragma unroll
        for (int j = 0; j < 64; ++j) g = fmaf(h1[j], sW1[k * 64 + j], g);
        if (z > 0.f) {
            nx = fmaf(g, sW0[k], nx);
            ny = fmaf(g, sW0[64 + k], ny);
            nz = fmaf(g, sW0[128 + k], nz);
        }
    }

    // ---- render MLP: feat(41) = [pts, r_d, nrm, latent] ----
    float r0 = 0.f, r1 = 0.f, r2 = 0.f;
    for (int u = 0; u < 64; ++u) {
        const float* w = &sRW0T[u * 48];
        float a = px * w[0] + py * w[1] + pz * w[2];
        a = fmaf(dx, w[3], a); a = fmaf(dy, w[4], a); a = fmaf(dz, w[5], a);
        a = fmaf(nx, w[6], a); a = fmaf(ny, w[7], a); a = fmaf(nz, w[8], a);
        #pragma unroll
        for (int q = 0; q < 32; ++q) a = fmaf(lat[q], w[9 + q], a);
        a += sRb0[u];
        const float ru = fmaxf(a, 0.f);
        r0 = fmaf(ru, sRW1[u * 3 + 0], r0);
        r1 = fmaf(ru, sRW1[u * 3 + 1], r1);
        r2 = fmaf(ru, sRW1[u * 3 + 2], r2);
    }
    r0 += sRb1[0]; r1 += sRb1[1]; r2 += sRb1[2];

    out[i * 3 + 0] = 1.f / (1.f + expf(-r0));
    out[i * 3 + 1] = 1.f / (1.f + expf(-r1));
    out[i * 3 + 2] = 1.f / (1.f + expf(-r2));
}

// ---------------------------------------------------------------------------
// Fallback path (only if workspace is too small for the queues).
// ---------------------------------------------------------------------------
__global__ __launch_bounds__(256, 2)
void march_kernel(const float* __restrict__ rays,
                  const float* __restrict__ W0, const float* __restrict__ b0,
                  const float* __restrict__ W1, const float* __restrict__ b1,
                  const float* __restrict__ W2, const float* __restrict__ b2,
                  float* __restrict__ t_out, int* __restrict__ hit_out,
                  int* __restrict__ counter)
{
    float ox = 0.f, oy = 0.f, oz = 0.f, rdx = 0.f, rdy = 0.f, rdz = 0.f;
    float cd = 0.f;
    int ridx = -1, it = 0;
    bool has = false, hit = false, exhausted = false;

    const float b2_0 = b2[0];

    while (true) {
        if (!has && !exhausted) {
            int idx = atomicAdd(counter, 1);
            if (idx < NRAYS) {
                const float* r = rays + (size_t)idx * 6;
                ox = r[0]; oy = r[1]; oz = r[2];
                rdx = r[3]; rdy = r[4]; rdz = r[5];
                cd = NEARV; it = 0; hit = false; has = true; ridx = idx;
            } else {
                exhausted = true;
            }
        }
        if (__ballot(has) == 0ull) break;

        const float px = ox + rdx * cd;
        const float py = oy + rdy * cd;
        const float pz = oz + rdz * cd;

        const float d = sdf_eval(px, py, pz, W0, b0, W1, b1, W2, b2_0);

        if (has) {
            ++it;
            if (d < EPSV && cd <= FARV) hit = true;
            cd += d;
            if (hit || cd > FARV || it >= MAXIT) {
                t_out[ridx] = cd;
                hit_out[ridx] = hit ? 1 : 0;
                has = false;
            }
        }
    }
}

__global__ __launch_bounds__(256, 2)
void shade_kernel(const float* __restrict__ rays,
                  const float* __restrict__ W0, const float* __restrict__ b0,
                  const float* __restrict__ W1, const float* __restrict__ b1,
                  const float* __restrict__ W2, const float* __restrict__ b2,
                  const float* __restrict__ RW0, const float* __restrict__ Rb0,
                  const float* __restrict__ RW1, const float* __restrict__ Rb1,
                  const float* __restrict__ t_in, const int* __restrict__ hit_in,
                  float* __restrict__ out)
{
    __shared__ float sW0[3 * 64];
    __shared__ float sb0[64];
    __shared__ float sW1[64 * 64];
    __shared__ float sb1[64];
    __shared__ float sW2T[33 * 64];
    __shared__ float sb2[33];
    __shared__ float sRW0T[64 * 48];
    __shared__ float sRb0[64];
    __shared__ float sRW1[64 * 3];
    __shared__ float sRb1[3];

    const int tid = threadIdx.x;
    for (int i = tid; i < 3 * 64; i += 256) sW0[i] = W0[i];
    for (int i = tid; i < 64 * 64; i += 256) sW1[i] = W1[i];
    for (int i = tid; i < 33 * 64; i += 256) {
        const int c = i >> 6, j = i & 63;
        sW2T[i] = W2[j * 33 + c];
    }
    for (int i = tid; i < 64 * 41; i += 256) {
        const int u = i / 41, f = i - u * 41;
        sRW0T[u * 48 + f] = RW0[f * 64 + u];
    }
    if (tid < 64) { sb0[tid] = b0[tid]; sb1[tid] = b1[tid]; sRb0[tid] = Rb0[tid]; }
    if (tid < 33) sb2[tid] = b2[tid];
    if (tid < 192) sRW1[tid] = RW1[tid];
    if (tid < 3) sRb1[tid] = Rb1[tid];
    __syncthreads();

    const int i = blockIdx.x * 256 + tid;
    const bool hit = hit_in[i] != 0;

    if (__ballot(hit) == 0ull) {
        out[i * 3 + 0] = 0.f;
        out[i * 3 + 1] = 0.f;
        out[i * 3 + 2] = 0.f;
        return;
    }

    const float* r = rays + (size_t)i * 6;
    const float cd = t_in[i];
    const float ox = r[0], oy = r[1], oz = r[2];
    const float dx = r[3], dy = r[4], dz = r[5];
    const float px = ox + dx * cd;
    const float py = oy + dy * cd;
    const float pz = oz + dz * cd;

    float h1[64];
    #pragma unroll
    for (int j = 0; j < 64; ++j) h1[j] = 0.f;

    for (int k = 0; k < 64; ++k) {
        float z = px * sW0[k] + py * sW0[64 + k] + pz * sW0[128 + k];
        z += sb0[k];
        const float a = fmaxf(z, 0.f);
        #pragma unroll
        for (int j = 0; j < 64; ++j) h1[j] = fmaf(a, sW1[k * 64 + j], h1[j]);
    }
    #pragma unroll
    for (int j = 0; j < 64; ++j) h1[j] = fmaxf(h1[j] + sb1[j], 0.f);

    float lat[32];
    #pragma unroll
    for (int c = 1; c < 33; ++c) {
        float acc = 0.f;
        #pragma unroll
        for (int j = 0; j < 64; ++j) acc = fmaf(h1[j], sW2T[c * 64 + j], acc);
        lat[c - 1] = acc + sb2[c];
    }

    #pragma unroll
    for (int j = 0; j < 64; ++j) h1[j] = (h1[j] > 0.f) ? sW2T[j] : 0.f;

    float nx = 0.f, ny = 0.f, nz = 0.f;
    for (int k = 0; k < 64; ++k) {
        float z = px * sW0[k] + py * sW0[64 + k] + pz * sW0[128 + k];
        z += sb0[k];
        float g = 0.f;
        #pragma unroll
        for (int j = 0; j < 64; ++j) g = fmaf(h1[j], sW1[k * 64 + j], g);
        if (z > 0.f) {
            nx = fmaf(g, sW0[k], nx);
            ny = fmaf(g, sW0[64 + k], ny);
            nz = fmaf(g, sW0[128 + k], nz);
        }
    }
    if (!hit) { nx = 0.f; ny = 0.f; nz = 0.f; }

    float r0 = 0.f, r1 = 0.f, r2 = 0.f;
    for (int u = 0; u < 64; ++u) {
        const float* w = &sRW0T[u * 48];
        float a = px * w[0] + py * w[1] + pz * w[2];
        a = fmaf(dx, w[3], a); a = fmaf(dy, w[4], a); a = fmaf(dz, w[5], a);
        a = fmaf(nx, w[6], a); a = fmaf(ny, w[7], a); a = fmaf(nz, w[8], a);
        #pragma unroll
        for (int q = 0; q < 32; ++q) a = fmaf(lat[q], w[9 + q], a);
        a += sRb0[u];
        const float ru = fmaxf(a, 0.f);
        r0 = fmaf(ru, sRW1[u * 3 + 0], r0);
        r1 = fmaf(ru, sRW1[u * 3 + 1], r1);
        r2 = fmaf(ru, sRW1[u * 3 + 2], r2);
    }
    r0 += sRb1[0]; r1 += sRb1[1]; r2 += sRb1[2];

    const float o0 = 1.f / (1.f + expf(-r0));
    const float o1 = 1.f / (1.f + expf(-r1));
    const float o2 = 1.f / (1.f + expf(-r2));

    out[i * 3 + 0] = hit ? o0 : 0.f;
    out[i * 3 + 1] = hit ? o1 : 0.f;
    out[i * 3 + 2] = hit ? o2 : 0.f;
}

extern "C" void kernel_launch(void* const* d_in, const int* in_sizes, int n_in,
                              void* d_out, int out_size, void* d_ws, size_t ws_size,
                              hipStream_t stream) {
    const float* rays = (const float*)d_in[0];
    const float* W0   = (const float*)d_in[1];
    const float* b0   = (const float*)d_in[2];
    const float* W1   = (const float*)d_in[3];
    const float* b1   = (const float*)d_in[4];
    const float* W2   = (const float*)d_in[5];
    const float* b2   = (const float*)d_in[6];
    const float* RW0  = (const float*)d_in[7];
    const float* Rb0  = (const float*)d_in[8];
    const float* RW1  = (const float*)d_in[9];
    const float* Rb1  = (const float*)d_in[10];

    // Workspace layout (4-byte units):
    //   [0..15]                    counters: cnt[r]=survivors after round r, cnt[15]=hit count
    //   [16          .. 16+N)      t
    //   [16+N        .. 16+2N)     queue A idx
    //   [16+2N       .. 16+3N)     queue A cd
    //   [16+3N       .. 16+4N)     queue B idx
    //   [16+4N       .. 16+5N)     queue B cd
    //   [16+5N       .. 16+6N)     hit queue
    const size_t need = (size_t)(16 + 6 * NRAYS) * 4;

    if (ws_size >= need) {
        int*   cnt  = (int*)d_ws;
        float* t_ws = (float*)d_ws + 16;
        int*   qiA  = (int*)d_ws + 16 + (size_t)NRAYS;
        float* qcA  = (float*)d_ws + 16 + 2 * (size_t)NRAYS;
        int*   qiB  = (int*)d_ws + 16 + 3 * (size_t)NRAYS;
        float* qcB  = (float*)d_ws + 16 + 4 * (size_t)NRAYS;
        int*   hitq = (int*)d_ws + 16 + 5 * (size_t)NRAYS;

        hipMemsetAsync(cnt, 0, 16 * sizeof(int), stream);
        hipMemsetAsync(d_out, 0, (size_t)out_size, stream);

        // 2 rays per lane -> NRAYS/512 blocks.
        const int blocks = NRAYS / 512;

        // Round 0: all rays fresh, survivors -> queue A (cnt[0]).
        march_round2<<<blocks, 256, 0, stream>>>(
            rays, W0, b0, W1, b1, W2, b2,
            1, 0, nullptr, nullptr, nullptr,
            &cnt[0], qiA, qcA, t_ws, hitq, &cnt[15]);

        for (int r2 = 1; r2 < NROUNDS; ++r2) {
            const int*   icnt = &cnt[r2 - 1];
            int*         ocnt = &cnt[r2];
            const int*   ii = (r2 & 1) ? qiA : qiB;
            const float* ic = (r2 & 1) ? qcA : qcB;
            int*         oi = (r2 & 1) ? qiB : qiA;
            float*       oc = (r2 & 1) ? qcB : qcA;
            march_round2<<<blocks, 256, 0, stream>>>(
                rays, W0, b0, W1, b1, W2, b2,
                0, r2 * KCHUNK, icnt, ii, ic,
                ocnt, oi, oc, t_ws, hitq, &cnt[15]);
        }

        shade_hit<<<NRAYS / 256, 256, 0, stream>>>(
            rays, W0, b0, W1, b1, W2, b2, RW0, Rb0, RW1, Rb1,
            t_ws, hitq, &cnt[15], (float*)d_out);
    } else {
        // Fallback: previous passing path.
        float* t_ws  = (float*)d_ws;
        int*   hit_ws = (int*)d_ws + NRAYS;
        int*   ctr    = (int*)d_ws + 2 * NRAYS;

        hipMemsetAsync(ctr, 0, sizeof(int), stream);
        march_kernel<<<1024, 256, 0, stream>>>(rays, W0, b0, W1, b1, W2, b2,
                                               t_ws, hit_ws, ctr);
        shade_kernel<<<NRAYS / 256, 256, 0, stream>>>(rays, W0, b0, W1, b1, W2, b2,
                                                      RW0, Rb0, RW1, Rb1,
                                                      t_ws, hit_ws, (float*)d_out);
    }
}

// Round 8
// 3705.081 us; speedup vs baseline: 2.0613x; 2.0613x over previous
//
#include <hip/hip_runtime.h>
#include <math.h>

#define NRAYS 262144
#define MAXIT 192
#define NEARV 0.2f
#define FARV  2.0f
#define EPSV  0.001f
#define KCHUNK 16
#define NROUNDS 12    // KCHUNK * NROUNDS == MAXIT
#define MBLK 512      // march block size (8 waves)

// ---------------------------------------------------------------------------
// Single-ray SDF MLP eval (fallback path only) — canonical fma order,
// scalar weight loads.
// ---------------------------------------------------------------------------
__device__ __forceinline__ float sdf_eval(
    float px, float py, float pz,
    const float* __restrict__ W0, const float* __restrict__ b0,
    const float* __restrict__ W1, const float* __restrict__ b1,
    const float* __restrict__ W2, float b2_0)
{
    float h1[64];
    #pragma unroll
    for (int j = 0; j < 64; ++j) h1[j] = 0.f;

    for (int k = 0; k < 64; ++k) {
        float z = px * W0[k] + py * W0[64 + k] + pz * W0[128 + k];
        z += b0[k];
        const float a = fmaxf(z, 0.f);
        #pragma unroll
        for (int j = 0; j < 64; ++j) h1[j] = fmaf(a, W1[k * 64 + j], h1[j]);
    }

    float d = 0.f;
    #pragma unroll
    for (int j = 0; j < 64; ++j)
        d = fmaf(fmaxf(h1[j] + b1[j], 0.f), W2[j * 33], d);
    return d + b2_0;
}

// ---------------------------------------------------------------------------
// Round-based march with wave PHASE-LOCKING (R6) at a 256-reg unified
// budget (the single change vs R6).
// Evidence: R6's s_barrier phase-lock raised VALUBusy 58.6->73.5% (K$
// window shared by all block waves), but __launch_bounds__(512,4) capped
// the UNIFIED VGPR+AGPR budget at 128 regs -> h1's 64 AGPRs didn't fit ->
// compiler j-split into half-rows and re-streamed z (+43% instructions,
// R2's signature). (512,2) gives 256 regs: R3 proved codegen stays
// single-pass at that budget. Expected: R1 instruction count at R6 issue
// efficiency -> ~434 us round-0.
// fma order identical to sdf_eval -> bit-identical t/hit.
// ---------------------------------------------------------------------------
__global__ __launch_bounds__(MBLK, 2)
void march_round(const float* __restrict__ rays,
                 const float* __restrict__ W0, const float* __restrict__ b0,
                 const float* __restrict__ W1, const float* __restrict__ b1,
                 const float* __restrict__ W2, const float* __restrict__ b2,
                 int round0, int it_base,
                 const int* __restrict__ in_cnt,
                 const int* __restrict__ in_idx, const float* __restrict__ in_cd,
                 int* __restrict__ out_cnt,
                 int* __restrict__ out_idx, float* __restrict__ out_cd,
                 float* __restrict__ t_out,
                 int* __restrict__ hitq, int* __restrict__ hit_cnt)
{
    const int i    = blockIdx.x * MBLK + threadIdx.x;
    const int lane = threadIdx.x & 63;
    const int n    = round0 ? NRAYS : *in_cnt;

    // Block-uniform early exit BEFORE any barrier (empty tail blocks).
    if (blockIdx.x * MBLK >= n) return;

    bool alive = (i < n);
    bool hit   = false;
    int  ridx  = 0;
    float cd   = NEARV;
    int  it    = it_base;

    if (alive) {
        if (round0) {
            ridx = i;
        } else {
            ridx = in_idx[i];
            cd   = in_cd[i];
        }
    }

    const float* r = rays + (size_t)ridx * 6;   // dead lanes read ray 0 (in-bounds)
    const float ox = r[0], oy = r[1], oz = r[2];
    const float rdx = r[3], rdy = r[4], rdz = r[5];
    const float b2_0 = b2[0];

    // Fixed trip count: every wave executes every barrier. (With ~50%/round
    // survival, P(a wave fully drains mid-round) ~ 0, so the lost early
    // break is immaterial — verified by R1-vs-R6 instruction accounting.)
    for (int s = 0; s < KCHUNK; ++s) {
        const float px = ox + rdx * cd;
        const float py = oy + rdy * cd;
        const float pz = oz + rdz * cd;

        float h1[64];
        #pragma unroll
        for (int j = 0; j < 64; ++j) h1[j] = 0.f;

        for (int kt = 0; kt < 8; ++kt) {
            #pragma unroll
            for (int kk = 0; kk < 8; ++kk) {
                const int k = kt * 8 + kk;
                float z = px * W0[k] + py * W0[64 + k] + pz * W0[128 + k];
                z += b0[k];
                const float a = fmaxf(z, 0.f);
                #pragma unroll
                for (int j = 0; j < 64; ++j)
                    h1[j] = fmaf(a, W1[k * 64 + j], h1[j]);
            }
            // Phase clamp only. No data crosses this barrier, so no
            // s_waitcnt drain (raw s_barrier, not __syncthreads).
            __builtin_amdgcn_s_barrier();
        }

        float d = 0.f;
        #pragma unroll
        for (int j = 0; j < 64; ++j)
            d = fmaf(fmaxf(h1[j] + b1[j], 0.f), W2[j * 33], d);
        d += b2_0;

        if (alive) {
            ++it;
            if (d < EPSV && cd <= FARV) hit = true;
            cd += d;
            if (hit || cd > FARV || it >= MAXIT) {
                t_out[ridx] = cd;
                if (hit) {
                    const int p = atomicAdd(hit_cnt, 1);
                    hitq[p] = ridx;
                }
                alive = false;
            }
        }
    }

    // Wave-aggregated compaction of survivors into the out-queue.
    const unsigned long long m = __ballot(alive);
    if (m != 0ull) {
        const int leader = __builtin_ctzll(m);
        int base = 0;
        if (lane == leader) base = atomicAdd(out_cnt, __builtin_popcountll(m));
        base = __shfl(base, leader);
        if (alive) {
            const int off = __builtin_popcountll(m & ((1ull << lane) - 1ull));
            out_idx[base + off] = ridx;
            out_cd[base + off]  = cd;
        }
    }
}

// ---------------------------------------------------------------------------
// Shade only the hit rays (dense hit queue). Output memset to zero.
// Bit-identical arithmetic to the passing shade kernel.
// ---------------------------------------------------------------------------
__global__ __launch_bounds__(256, 2)
void shade_hit(const float* __restrict__ rays,
               const float* __restrict__ W0, const float* __restrict__ b0,
               const float* __restrict__ W1, const float* __restrict__ b1,
               const float* __restrict__ W2, const float* __restrict__ b2,
               const float* __restrict__ RW0, const float* __restrict__ Rb0,
               const float* __restrict__ RW1, const float* __restrict__ Rb1,
               const float* __restrict__ t_in,
               const int* __restrict__ hitq, const int* __restrict__ hit_cnt,
               float* __restrict__ out)
{
    const int n = *hit_cnt;
    if (blockIdx.x * 256 >= n) return;   // whole block empty -> skip staging

    __shared__ float sW0[3 * 64];
    __shared__ float sb0[64];
    __shared__ float sW1[64 * 64];
    __shared__ float sb1[64];
    __shared__ float sW2T[33 * 64];   // [c][j] = W2[j][c]
    __shared__ float sb2[33];
    __shared__ float sRW0T[64 * 48];  // [u][f] = RW0[f][u], padded 41->48
    __shared__ float sRb0[64];
    __shared__ float sRW1[64 * 3];
    __shared__ float sRb1[3];

    const int tid = threadIdx.x;
    for (int i = tid; i < 3 * 64; i += 256) sW0[i] = W0[i];
    for (int i = tid; i < 64 * 64; i += 256) sW1[i] = W1[i];
    for (int i = tid; i < 33 * 64; i += 256) {
        const int c = i >> 6, j = i & 63;
        sW2T[i] = W2[j * 33 + c];
    }
    for (int i = tid; i < 64 * 41; i += 256) {
        const int u = i / 41, f = i - u * 41;
        sRW0T[u * 48 + f] = RW0[f * 64 + u];
    }
    if (tid < 64) { sb0[tid] = b0[tid]; sb1[tid] = b1[tid]; sRb0[tid] = Rb0[tid]; }
    if (tid < 33) sb2[tid] = b2[tid];
    if (tid < 192) sRW1[tid] = RW1[tid];
    if (tid < 3) sRb1[tid] = Rb1[tid];
    __syncthreads();

    const int qi = blockIdx.x * 256 + tid;
    if (qi >= n) return;
    const int i = hitq[qi];

    const float* r = rays + (size_t)i * 6;
    const float cd = t_in[i];
    const float ox = r[0], oy = r[1], oz = r[2];
    const float dx = r[3], dy = r[4], dz = r[5];
    const float px = ox + dx * cd;
    const float py = oy + dy * cd;
    const float pz = oz + dz * cd;

    // ---- forward, layer 1 accumulation ----
    float h1[64];
    #pragma unroll
    for (int j = 0; j < 64; ++j) h1[j] = 0.f;

    for (int k = 0; k < 64; ++k) {
        float z = px * sW0[k] + py * sW0[64 + k] + pz * sW0[128 + k];
        z += sb0[k];
        const float a = fmaxf(z, 0.f);
        #pragma unroll
        for (int j = 0; j < 64; ++j) h1[j] = fmaf(a, sW1[k * 64 + j], h1[j]);
    }
    #pragma unroll
    for (int j = 0; j < 64; ++j) h1[j] = fmaxf(h1[j] + sb1[j], 0.f);

    // ---- latent = out[:,1:33] ----
    float lat[32];
    #pragma unroll
    for (int c = 1; c < 33; ++c) {
        float acc = 0.f;
        #pragma unroll
        for (int j = 0; j < 64; ++j) acc = fmaf(h1[j], sW2T[c * 64 + j], acc);
        lat[c - 1] = acc + sb2[c];
    }

    // ---- backward: gz1 = (z1>0) ? W2[:,0] : 0 ----
    #pragma unroll
    for (int j = 0; j < 64; ++j) h1[j] = (h1[j] > 0.f) ? sW2T[j] : 0.f;

    float nx = 0.f, ny = 0.f, nz = 0.f;
    for (int k = 0; k < 64; ++k) {
        float z = px * sW0[k] + py * sW0[64 + k] + pz * sW0[128 + k];
        z += sb0[k];
        float g = 0.f;
        #pragma unroll
        for (int j = 0; j < 64; ++j) g = fmaf(h1[j], sW1[k * 64 + j], g);
        if (z > 0.f) {
            nx = fmaf(g, sW0[k], nx);
            ny = fmaf(g, sW0[64 + k], ny);
            nz = fmaf(g, sW0[128 + k], nz);
        }
    }

    // ---- render MLP: feat(41) = [pts, r_d, nrm, latent] ----
    float r0 = 0.f, r1 = 0.f, r2 = 0.f;
    for (int u = 0; u < 64; ++u) {
        const float* w = &sRW0T[u * 48];
        float a = px * w[0] + py * w[1] + pz * w[2];
        a = fmaf(dx, w[3], a); a = fmaf(dy, w[4], a); a = fmaf(dz, w[5], a);
        a = fmaf(nx, w[6], a); a = fmaf(ny, w[7], a); a = fmaf(nz, w[8], a);
        #pragma unroll
        for (int q = 0; q < 32; ++q) a = fmaf(lat[q], w[9 + q], a);
        a += sRb0[u];
        const float ru = fmaxf(a, 0.f);
        r0 = fmaf(ru, sRW1[u * 3 + 0], r0);
        r1 = fmaf(ru, sRW1[u * 3 + 1], r1);
        r2 = fmaf(ru, sRW1[u * 3 + 2], r2);
    }
    r0 += sRb1[0]; r1 += sRb1[1]; r2 += sRb1[2];

    out[i * 3 + 0] = 1.f / (1.f + expf(-r0));
    out[i * 3 + 1] = 1.f / (1.f + expf(-r1));
    out[i * 3 + 2] = 1.f / (1.f + expf(-r2));
}

// ---------------------------------------------------------------------------
// Fallback path (only if workspace is too small for the queues).
// ---------------------------------------------------------------------------
__global__ __launch_bounds__(256, 2)
void march_kernel(const float* __restrict__ rays,
                  const float* __restrict__ W0, const float* __restrict__ b0,
                  const float* __restrict__ W1, const float* __restrict__ b1,
                  const float* __restrict__ W2, const float* __restrict__ b2,
                  float* __restrict__ t_out, int* __restrict__ hit_out,
                  int* __restrict__ counter)
{
    float ox = 0.f, oy = 0.f, oz = 0.f, rdx = 0.f, rdy = 0.f, rdz = 0.f;
    float cd = 0.f;
    int ridx = -1, it = 0;
    bool has = false, hit = false, exhausted = false;

    const float b2_0 = b2[0];

    while (true) {
        if (!has && !exhausted) {
            int idx = atomicAdd(counter, 1);
            if (idx < NRAYS) {
                const float* r = rays + (size_t)idx * 6;
                ox = r[0]; oy = r[1]; oz = r[2];
                rdx = r[3]; rdy = r[4]; rdz = r[5];
                cd = NEARV; it = 0; hit = false; has = true; ridx = idx;
            } else {
                exhausted = true;
            }
        }
        if (__ballot(has) == 0ull) break;

        const float px = ox + rdx * cd;
        const float py = oy + rdy * cd;
        const float pz = oz + rdz * cd;

        const float d = sdf_eval(px, py, pz, W0, b0, W1, b1, W2, b2_0);

        if (has) {
            ++it;
            if (d < EPSV && cd <= FARV) hit = true;
            cd += d;
            if (hit || cd > FARV || it >= MAXIT) {
                t_out[ridx] = cd;
                hit_out[ridx] = hit ? 1 : 0;
                has = false;
            }
        }
    }
}

__global__ __launch_bounds__(256, 2)
void shade_kernel(const float* __restrict__ rays,
                  const float* __restrict__ W0, const float* __restrict__ b0,
                  const float* __restrict__ W1, const float* __restrict__ b1,
                  const float* __restrict__ W2, const float* __restrict__ b2,
                  const float* __restrict__ RW0, const float* __restrict__ Rb0,
                  const float* __restrict__ RW1, const float* __restrict__ Rb1,
                  const float* __restrict__ t_in, const int* __restrict__ hit_in,
                  float* __restrict__ out)
{
    __shared__ float sW0[3 * 64];
    __shared__ float sb0[64];
    __shared__ float sW1[64 * 64];
    __shared__ float sb1[64];
    __shared__ float sW2T[33 * 64];
    __shared__ float sb2[33];
    __shared__ float sRW0T[64 * 48];
    __shared__ float sRb0[64];
    __shared__ float sRW1[64 * 3];
    __shared__ float sRb1[3];

    const int tid = threadIdx.x;
    for (int i = tid; i < 3 * 64; i += 256) sW0[i] = W0[i];
    for (int i = tid; i < 64 * 64; i += 256) sW1[i] = W1[i];
    for (int i = tid; i < 33 * 64; i += 256) {
        const int c = i >> 6, j = i & 63;
        sW2T[i] = W2[j * 33 + c];
    }
    for (int i = tid; i < 64 * 41; i += 256) {
        const int u = i / 41, f = i - u * 41;
        sRW0T[u * 48 + f] = RW0[f * 64 + u];
    }
    if (tid < 64) { sb0[tid] = b0[tid]; sb1[tid] = b1[tid]; sRb0[tid] = Rb0[tid]; }
    if (tid < 33) sb2[tid] = b2[tid];
    if (tid < 192) sRW1[tid] = RW1[tid];
    if (tid < 3) sRb1[tid] = Rb1[tid];
    __syncthreads();

    const int i = blockIdx.x * 256 + tid;
    const bool hit = hit_in[i] != 0;

    if (__ballot(hit) == 0ull) {
        out[i * 3 + 0] = 0.f;
        out[i * 3 + 1] = 0.f;
        out[i * 3 + 2] = 0.f;
        return;
    }

    const float* r = rays + (size_t)i * 6;
    const float cd = t_in[i];
    const float ox = r[0], oy = r[1], oz = r[2];
    const float dx = r[3], dy = r[4], dz = r[5];
    const float px = ox + dx * cd;
    const float py = oy + dy * cd;
    const float pz = oz + dz * cd;

    float h1[64];
    #pragma unroll
    for (int j = 0; j < 64; ++j) h1[j] = 0.f;

    for (int k = 0; k < 64; ++k) {
        float z = px * sW0[k] + py * sW0[64 + k] + pz * sW0[128 + k];
        z += sb0[k];
        const float a = fmaxf(z, 0.f);
        #pragma unroll
        for (int j = 0; j < 64; ++j) h1[j] = fmaf(a, sW1[k * 64 + j], h1[j]);
    }
    #pragma unroll
    for (int j = 0; j < 64; ++j) h1[j] = fmaxf(h1[j] + sb1[j], 0.f);

    float lat[32];
    #pragma unroll
    for (int c = 1; c < 33; ++c) {
        float acc = 0.f;
        #pragma unroll
        for (int j = 0; j < 64; ++j) acc = fmaf(h1[j], sW2T[c * 64 + j], acc);
        lat[c - 1] = acc + sb2[c];
    }

    #pragma unroll
    for (int j = 0; j < 64; ++j) h1[j] = (h1[j] > 0.f) ? sW2T[j] : 0.f;

    float nx = 0.f, ny = 0.f, nz = 0.f;
    for (int k = 0; k < 64; ++k) {
        float z = px * sW0[k] + py * sW0[64 + k] + pz * sW0[128 + k];
        z += sb0[k];
        float g = 0.f;
        #pragma unroll
        for (int j = 0; j < 64; ++j) g = fmaf(h1[j], sW1[k * 64 + j], g);
        if (z > 0.f) {
            nx = fmaf(g, sW0[k], nx);
            ny = fmaf(g, sW0[64 + k], ny);
            nz = fmaf(g, sW0[128 + k], nz);
        }
    }
    if (!hit) { nx = 0.f; ny = 0.f; nz = 0.f; }

    float r0 = 0.f, r1 = 0.f, r2 = 0.f;
    for (int u = 0; u < 64; ++u) {
        const float* w = &sRW0T[u * 48];
        float a = px * w[0] + py * w[1] + pz * w[2];
        a = fmaf(dx, w[3], a); a = fmaf(dy, w[4], a); a = fmaf(dz, w[5], a);
        a = fmaf(nx, w[6], a); a = fmaf(ny, w[7], a); a = fmaf(nz, w[8], a);
        #pragma unroll
        for (int q = 0; q < 32; ++q) a = fmaf(lat[q], w[9 + q], a);
        a += sRb0[u];
        const float ru = fmaxf(a, 0.f);
        r0 = fmaf(ru, sRW1[u * 3 + 0], r0);
        r1 = fmaf(ru, sRW1[u * 3 + 1], r1);
        r2 = fmaf(ru, sRW1[u * 3 + 2], r2);
    }
    r0 += sRb1[0]; r1 += sRb1[1]; r2 += sRb1[2];

    const float o0 = 1.f / (1.f + expf(-r0));
    const float o1 = 1.f / (1.f + expf(-r1));
    const float o2 = 1.f / (1.f + expf(-r2));

    out[i * 3 + 0] = hit ? o0 : 0.f;
    out[i * 3 + 1] = hit ? o1 : 0.f;
    out[i * 3 + 2] = hit ? o2 : 0.f;
}

extern "C" void kernel_launch(void* const* d_in, const int* in_sizes, int n_in,
                              void* d_out, int out_size, void* d_ws, size_t ws_size,
                              hipStream_t stream) {
    const float* rays = (const float*)d_in[0];
    const float* W0   = (const float*)d_in[1];
    const float* b0   = (const float*)d_in[2];
    const float* W1   = (const float*)d_in[3];
    const float* b1   = (const float*)d_in[4];
    const float* W2   = (const float*)d_in[5];
    const float* b2   = (const float*)d_in[6];
    const float* RW0  = (const float*)d_in[7];
    const float* Rb0  = (const float*)d_in[8];
    const float* RW1  = (const float*)d_in[9];
    const float* Rb1  = (const float*)d_in[10];

    // Workspace layout (4-byte units):
    //   [0..15]                    counters: cnt[r]=survivors after round r, cnt[15]=hit count
    //   [16          .. 16+N)      t
    //   [16+N        .. 16+2N)     queue A idx
    //   [16+2N       .. 16+3N)     queue A cd
    //   [16+3N       .. 16+4N)     queue B idx
    //   [16+4N       .. 16+5N)     queue B cd
    //   [16+5N       .. 16+6N)     hit queue
    const size_t need = (size_t)(16 + 6 * NRAYS) * 4;

    if (ws_size >= need) {
        int*   cnt  = (int*)d_ws;
        float* t_ws = (float*)d_ws + 16;
        int*   qiA  = (int*)d_ws + 16 + (size_t)NRAYS;
        float* qcA  = (float*)d_ws + 16 + 2 * (size_t)NRAYS;
        int*   qiB  = (int*)d_ws + 16 + 3 * (size_t)NRAYS;
        float* qcB  = (float*)d_ws + 16 + 4 * (size_t)NRAYS;
        int*   hitq = (int*)d_ws + 16 + 5 * (size_t)NRAYS;

        hipMemsetAsync(cnt, 0, 16 * sizeof(int), stream);
        hipMemsetAsync(d_out, 0, (size_t)out_size, stream);

        const int blocks = NRAYS / MBLK;

        // Round 0: all rays fresh, survivors -> queue A (cnt[0]).
        march_round<<<blocks, MBLK, 0, stream>>>(
            rays, W0, b0, W1, b1, W2, b2,
            1, 0, nullptr, nullptr, nullptr,
            &cnt[0], qiA, qcA, t_ws, hitq, &cnt[15]);

        for (int r2 = 1; r2 < NROUNDS; ++r2) {
            const int*   icnt = &cnt[r2 - 1];
            int*         ocnt = &cnt[r2];
            const int*   ii = (r2 & 1) ? qiA : qiB;
            const float* ic = (r2 & 1) ? qcA : qcB;
            int*         oi = (r2 & 1) ? qiB : qiA;
            float*       oc = (r2 & 1) ? qcB : qcA;
            march_round<<<blocks, MBLK, 0, stream>>>(
                rays, W0, b0, W1, b1, W2, b2,
                0, r2 * KCHUNK, icnt, ii, ic,
                ocnt, oi, oc, t_ws, hitq, &cnt[15]);
        }

        shade_hit<<<NRAYS / 256, 256, 0, stream>>>(
            rays, W0, b0, W1, b1, W2, b2, RW0, Rb0, RW1, Rb1,
            t_ws, hitq, &cnt[15], (float*)d_out);
    } else {
        // Fallback: previous passing path.
        float* t_ws  = (float*)d_ws;
        int*   hit_ws = (int*)d_ws + NRAYS;
        int*   ctr    = (int*)d_ws + 2 * NRAYS;

        hipMemsetAsync(ctr, 0, sizeof(int), stream);
        march_kernel<<<1024, 256, 0, stream>>>(rays, W0, b0, W1, b1, W2, b2,
                                               t_ws, hit_ws, ctr);
        shade_kernel<<<NRAYS / 256, 256, 0, stream>>>(rays, W0, b0, W1, b1, W2, b2,
                                                      RW0, Rb0, RW1, Rb1,
                                                      t_ws, hit_ws, (float*)d_out);
    }
}